// Round 17
// baseline (123.053 us; speedup 1.0000x reference)
//
#include <hip/hip_runtime.h>
#include <hip/hip_bf16.h>
#include <stdint.h>

#define M_DIM 8192
#define N_DIM 2048
#define K_DIM 2048

typedef __attribute__((ext_vector_type(8))) short bf16x8;
typedef __attribute__((ext_vector_type(8))) short short8;
typedef __attribute__((ext_vector_type(4))) float f32x4;

static __device__ __forceinline__ unsigned short f2bf(float f) {
  union { float f; unsigned u; } a; a.f = f;
  unsigned u = a.u;
  u += 0x7FFFu + ((u >> 16) & 1u);   // round-to-nearest-even
  return (unsigned short)(u >> 16);
}

static __device__ __forceinline__ void async16(void* lds, const void* g) {
  __builtin_amdgcn_global_load_lds(
      (const __attribute__((address_space(1))) unsigned int*)g,
      (__attribute__((address_space(3))) unsigned int*)lds, 16, 0, 0);
}

#define BAR()                                \
  do {                                       \
    asm volatile("" ::: "memory");           \
    __builtin_amdgcn_s_barrier();            \
    asm volatile("" ::: "memory");           \
  } while (0)
#define VMCNT(n) asm volatile("s_waitcnt vmcnt(" #n ")" ::: "memory")

// ---- kernel 1: fused prep (round-14 validated, ~18 us, at BW floor) ----
__global__ __launch_bounds__(256) void k_prep(const float* __restrict__ W,
    const float* __restrict__ X, const float* __restrict__ b,
    unsigned short* __restrict__ Wt, unsigned short* __restrict__ Xb,
    float* __restrict__ adj) {
  __shared__ float smem[64 * 65];
  const int t = threadIdx.x;
  if (blockIdx.x < 1024) {
    float (*tile)[65] = (float (*)[65])smem;
    const int bx = blockIdx.x & 31;
    const int by = blockIdx.x >> 5;
    const int n0 = bx * 64, k0 = by * 64;
    #pragma unroll
    for (int i = 0; i < 16; ++i) {
      int lin = i * 256 + t;
      int rr = lin >> 6, c = lin & 63;
      tile[rr][c] = W[(size_t)(k0 + rr) * N_DIM + n0 + c];
    }
    __syncthreads();
    #pragma unroll
    for (int i = 0; i < 16; ++i) {
      int lin = i * 256 + t;
      int rr = lin >> 6, c = lin & 63;
      Wt[(size_t)(n0 + rr) * K_DIM + k0 + c] = f2bf(tile[c][rr]);
    }
  } else {
    float* wlds = smem;
    double* red2 = (double*)(smem + 2048);
    const int m0r = (blockIdx.x - 1024) * 16;
    const int w = t >> 6;
    #pragma unroll
    for (int i = 0; i < 8; ++i)
      wlds[t * 8 + i] = W[(size_t)(t * 8 + i) * N_DIM];
    __syncthreads();
    const float4 wv0 = *(const float4*)&wlds[t * 8];
    const float4 wv1 = *(const float4*)&wlds[t * 8 + 4];
    for (int rr = 0; rr < 16; ++rr) {
      const int m = m0r + rr;
      const float4* xr = (const float4*)(X + (size_t)m * K_DIM);
      float4 x0 = xr[2 * t], x1 = xr[2 * t + 1];
      short8 o;
      o[0] = (short)f2bf(x0.x); o[1] = (short)f2bf(x0.y);
      o[2] = (short)f2bf(x0.z); o[3] = (short)f2bf(x0.w);
      o[4] = (short)f2bf(x1.x); o[5] = (short)f2bf(x1.y);
      o[6] = (short)f2bf(x1.z); o[7] = (short)f2bf(x1.w);
      *(short8*)(Xb + (size_t)m * K_DIM + t * 8) = o;
      double s = (double)x0.x * wv0.x + (double)x0.y * wv0.y +
                 (double)x0.z * wv0.z + (double)x0.w * wv0.w +
                 (double)x1.x * wv1.x + (double)x1.y * wv1.y +
                 (double)x1.z * wv1.z + (double)x1.w * wv1.w;
      #pragma unroll
      for (int off = 32; off > 0; off >>= 1) s += __shfl_down(s, off, 64);
      if ((t & 63) == 0) red2[rr * 4 + w] = s;
    }
    __syncthreads();
    if (t < 16) {
      double tot = red2[t * 4] + red2[t * 4 + 1] + red2[t * 4 + 2] +
                   red2[t * 4 + 3] + (double)b[0];
      adj[m0r + t] = (tot > 0.5) ? 1.0f : -1.0f;
    }
  }
}

// ---- kernel 2: 256x256 8-phase GEMM, B DIRECT FROM L2 (no B LDS) ----
// r13 skeleton (phases/BARs/A-path/streamed epilogue) preserved. B frags
// read straight from global (16 rows x 64B coalesced per b128 instr; B
// panel 1MB/block, L2/L3-resident; 2 waves/wn share addrs -> L1 dedupe).
// LDS: A only, 2 x 32KB. LDS reads 24->16 b128/wave/K-tile, writes halved.
// B double-buffered in regs: bvE (even tiles) / bvO (odd tiles).
//   GB(bvO,2i+1)@ph1 (used ph5, 4-phase lead); GB(bvE,2i+2)@ph5 (used next
//   ph1). A stages: A1(t1)@ph2, A0(t2)@ph3, A1(t2)@ph6, A0(t3)@ph7.
// Mixed vmcnt FIFO trace (steady X=12 outstanding: [bvE x8, A1e x2, A0o x2]):
//   vmcnt(10)@ph2 retires prev [bvE,A1(2i),A0(2i+1)] (A1 read ph3, A0 ph5)
//   vmcnt(12)@ph6 retires [bvO x8, A1(t1) x2]        (A1(t1) read ph7)
//   vmcnt(12)@ph8 retires [A0(t2) x2]                (read next ph1)
// Every stage->retire >= 3 phases; B reg-loads additionally auto-waited by
// compiler at first use. BARs carry "memory" clobbers -> no cross-phase
// load reordering.
__device__ __forceinline__ void stage_unitA(char* ldsc,
    const unsigned short* __restrict__ src, int row0, int kt,
    int sel, int wid, int l) {
  char* base = ldsc + (size_t)(kt & 1) * 32768;
  #pragma unroll
  for (int j = 0; j < 2; ++j) {
    int s = wid * 2 + j;
    int sub_c = s & 1;
    int idx = s >> 1;
    int sub_r = (idx & 3) + ((idx & 4) ? 8 : 0) + sel * 4;
    int grow = row0 + sub_r * 16 + (l >> 2);
    int gcol = kt * 64 + sub_c * 32 + (((l & 3) * 8) ^ ((l & 32) >> 1));
    async16(base + (size_t)(sub_r * 2 + sub_c) * 1024,
            src + (size_t)grow * K_DIM + gcol);
  }
}

__global__ __launch_bounds__(512, 1) void k_gemm8b(
    const unsigned short* __restrict__ A,   // Xb [M][K] bf16
    const unsigned short* __restrict__ B,   // Wt [N][K] bf16
    const float* __restrict__ bias,
    const float* __restrict__ adj,
    float* __restrict__ out) {
  __shared__ unsigned short lds[2 * 256 * 64];   // 64 KB, A only
  char* ldsc = (char*)lds;

  const int t = threadIdx.x;
  const int wid = t >> 6, l = t & 63;
  const int wm = wid >> 2, wn = wid & 3;

  // XCD-bijective swizzle (nwg = 256, 256 % 8 == 0)
  const int bid = blockIdx.x;
  const int swz = (bid & 7) * 32 + (bid >> 3);
  const int bm = swz >> 3, bn = swz & 7;
  const int m0 = bm * 256, n0 = bn * 256;

  const int r = l & 15, q = l >> 4;
  const int rdoff = (r * 64 + q * 16) ^ ((r & 8) << 2);

  const char* ab0 = ldsc;
  const char* ab1 = ldsc + 32768;

  // per-lane B base: row component (n0 + wn*64 + r) and k component (q*8)
  const unsigned short* Bln = B + (size_t)(n0 + wn * 64 + r) * K_DIM + q * 8;

  f32x4 acc[8][4] = {};
  bf16x8 af0[2][4], af1[2][4];
  bf16x8 bvE[2][4], bvO[2][4];     // [ks][nj], nj = NH*2+ni2

#define STG_A(sel, kt) stage_unitA(ldsc, A, m0, kt, sel, wid, l)

#define GB(DST, kt)                                                         \
  _Pragma("unroll") for (int nj = 0; nj < 4; ++nj)                          \
    _Pragma("unroll") for (int ks = 0; ks < 2; ++ks)                        \
      DST[ks][nj] = *(const bf16x8*)(Bln + (size_t)(nj * 16) * K_DIM +      \
                                     (kt) * 64 + ks * 32);

#define RD_A(DST, MH, AB)                                                   \
  _Pragma("unroll") for (int mi4 = 0; mi4 < 4; ++mi4) {                     \
    const int sub_r = wm * 8 + (MH) * 4 + mi4;                              \
    _Pragma("unroll") for (int ks = 0; ks < 2; ++ks)                        \
      DST[ks][mi4] =                                                        \
          *(const bf16x8*)((AB) + (size_t)(sub_r * 2 + ks) * 1024 + rdoff); \
  }

#define CL(MH, NH, AF, BV)                                                  \
  __builtin_amdgcn_s_setprio(1);                                            \
  _Pragma("unroll") for (int ks = 0; ks < 2; ++ks)                          \
    _Pragma("unroll") for (int mi4 = 0; mi4 < 4; ++mi4)                     \
      _Pragma("unroll") for (int ni2 = 0; ni2 < 2; ++ni2)                   \
        acc[(MH) * 4 + mi4][(NH) * 2 + ni2] =                               \
            __builtin_amdgcn_mfma_f32_16x16x32_bf16(                        \
                AF[ks][mi4], BV[ks][(NH) * 2 + ni2],                        \
                acc[(MH) * 4 + mi4][(NH) * 2 + ni2], 0, 0, 0);              \
  __builtin_amdgcn_s_setprio(0);

#define STQ(MH, NH)                                                         \
  _Pragma("unroll") for (int mi4 = 0; mi4 < 4; ++mi4)                       \
    _Pragma("unroll") for (int ni2 = 0; ni2 < 2; ++ni2) {                   \
      const int mi = (MH) * 4 + mi4, ni = (NH) * 2 + ni2;                   \
      const int col = n0 + wn * 64 + ni * 16 + r;                           \
      const int rowb = m0 + wm * 128 + mi * 16 + q * 4;                     \
      _Pragma("unroll") for (int j = 0; j < 4; ++j)                         \
        out[(size_t)(rowb + j) * N_DIM + col] =                             \
            acc[mi][ni][j] + bias_r[ni] + adj_r[mi][j];                     \
    }

#define PH(RD_STMT, STG_STMT, CL_STMT, WAIT_STMT)                           \
  {                                                                         \
    RD_STMT;                                                                \
    STG_STMT;                                                               \
    BAR();                                                                  \
    CL_STMT;                                                                \
    WAIT_STMT;                                                              \
    BAR();                                                                  \
  }

  // ---- prologue: B(0) regs + A(0) full + A0(1); drain ----
  GB(bvE, 0);
  STG_A(0, 0); STG_A(1, 0); STG_A(0, 1);
  VMCNT(0);
  BAR();

  // ---- main loop: 15 iters, tiles 2i (buf0,bvE) and 2i+1 (buf1,bvO) ----
  for (int i = 0; i < 15; ++i) {
    const int t1 = 2 * i + 1, t2 = 2 * i + 2, t3 = 2 * i + 3;
    PH(RD_A(af0, 0, ab0), GB(bvO, t1), CL(0, 0, af0, bvE), );     // ph1
    PH(, STG_A(1, t1), CL(0, 1, af0, bvE), VMCNT(10));            // ph2
    PH(RD_A(af1, 1, ab0), STG_A(0, t2), CL(1, 0, af1, bvE), );    // ph3
    PH(, , CL(1, 1, af1, bvE), );                                 // ph4
    PH(RD_A(af0, 0, ab1), GB(bvE, t2), CL(0, 0, af0, bvO), );     // ph5
    PH(, STG_A(1, t2), CL(0, 1, af0, bvO), VMCNT(12));            // ph6
    PH(RD_A(af1, 1, ab1), STG_A(0, t3), CL(1, 0, af1, bvO), );    // ph7
    PH(, , CL(1, 1, af1, bvO), VMCNT(12));                        // ph8
  }
  // ---- peeled tile 30 (buf0, bvE) ----
  PH(RD_A(af0, 0, ab0), GB(bvO, 31), CL(0, 0, af0, bvE), );
  PH(, STG_A(1, 31), CL(0, 1, af0, bvE), );
  PH(RD_A(af1, 1, ab0), , CL(1, 0, af1, bvE), );
  PH(, , CL(1, 1, af1, bvE), VMCNT(0));          // everything landed

  // ---- prefetch adj/bias (after last manual VMCNT) ----
  float4 adj_r[8];
  float bias_r[4];
  #pragma unroll
  for (int mi = 0; mi < 8; ++mi)
    adj_r[mi] = *(const float4*)&adj[m0 + wm * 128 + mi * 16 + q * 4];
  #pragma unroll
  for (int ni = 0; ni < 4; ++ni)
    bias_r[ni] = bias[n0 + wn * 64 + ni * 16 + r];

  // ---- peeled tile 31 (buf1, bvO): streamed epilogue ----
  PH(RD_A(af0, 0, ab1), , CL(0, 0, af0, bvO); STQ(0, 0), );
  PH(, , CL(0, 1, af0, bvO); STQ(0, 1), );
  PH(RD_A(af1, 1, ab1), , CL(1, 0, af1, bvO); STQ(1, 0), );
  {
    CL(1, 1, af1, bvO);
    STQ(1, 1);
  }

#undef PH
#undef STQ
#undef CL
#undef RD_A
#undef GB
#undef STG_A
}

// ---- fallback path (ws too small): fp32 LDS-tiled GEMM + row adjust ----
__global__ __launch_bounds__(256) void k_gemm_f32(const float* __restrict__ X,
    const float* __restrict__ W, const float* __restrict__ b,
    float* __restrict__ out) {
  __shared__ float As[16][16];
  __shared__ float Bs[16][17];
  const int bn = blockIdx.x & 127, bm = blockIdx.x >> 7;
  const int tx = threadIdx.x & 15, ty = threadIdx.x >> 4;
  const int row = bm * 16 + ty, col = bn * 16 + tx;
  float acc = 0.f;
  for (int k0 = 0; k0 < K_DIM; k0 += 16) {
    As[ty][tx] = X[(size_t)row * K_DIM + k0 + tx];
    Bs[ty][tx] = W[(size_t)(k0 + ty) * N_DIM + col];
    __syncthreads();
    #pragma unroll
    for (int kk = 0; kk < 16; ++kk) acc += As[ty][kk] * Bs[kk][tx];
    __syncthreads();
  }
  out[(size_t)row * N_DIM + col] = acc + b[col];
}

__global__ __launch_bounds__(256) void k_rowadj(float* __restrict__ out) {
  const int m = blockIdx.x;
  const float c0 = out[(size_t)m * N_DIM];
  __syncthreads();
  const float a = (c0 > 0.5f) ? 1.0f : -1.0f;
  for (int n = threadIdx.x; n < N_DIM; n += 256)
    out[(size_t)m * N_DIM + n] += a;
}

extern "C" void kernel_launch(void* const* d_in, const int* in_sizes, int n_in,
                              void* d_out, int out_size, void* d_ws, size_t ws_size,
                              hipStream_t stream) {
  const float* X = (const float*)d_in[0];
  const float* W = (const float*)d_in[1];
  const float* b = (const float*)d_in[2];
  float* out = (float*)d_out;

  const size_t XB_OFF   = 0;
  const size_t WT_OFF   = (size_t)M_DIM * K_DIM * 2;        // 32 MB
  const size_t ADJ_OFF  = WT_OFF + (size_t)N_DIM * K_DIM * 2;
  const size_t NEED     = ADJ_OFF + (size_t)M_DIM * 4;      // ~40 MB

  if (ws_size >= NEED) {
    unsigned short* Xb  = (unsigned short*)((char*)d_ws + XB_OFF);
    unsigned short* Wt  = (unsigned short*)((char*)d_ws + WT_OFF);
    float* adj  = (float*)((char*)d_ws + ADJ_OFF);
    k_prep<<<dim3(1536), dim3(256), 0, stream>>>(W, X, b, Wt, Xb, adj);
    k_gemm8b<<<dim3((M_DIM / 256) * (N_DIM / 256)), dim3(512), 0, stream>>>(
        Xb, Wt, b, adj, out);
  } else {
    k_gemm_f32<<<dim3((M_DIM / 16) * (N_DIM / 16)), dim3(256), 0, stream>>>(
        X, W, b, out);
    k_rowadj<<<dim3(M_DIM), dim3(256), 0, stream>>>(out);
  }
}

// Round 18
// 88.455 us; speedup vs baseline: 1.3911x; 1.3911x over previous
//
#include <hip/hip_runtime.h>
#include <hip/hip_bf16.h>
#include <stdint.h>

#define M_DIM 8192
#define N_DIM 2048
#define K_DIM 2048

typedef __attribute__((ext_vector_type(8))) short bf16x8;
typedef __attribute__((ext_vector_type(8))) short short8;
typedef __attribute__((ext_vector_type(4))) float f32x4;

static __device__ __forceinline__ unsigned short f2bf(float f) {
  union { float f; unsigned u; } a; a.f = f;
  unsigned u = a.u;
  u += 0x7FFFu + ((u >> 16) & 1u);   // round-to-nearest-even
  return (unsigned short)(u >> 16);
}

static __device__ __forceinline__ void async16(void* lds, const void* g) {
  __builtin_amdgcn_global_load_lds(
      (const __attribute__((address_space(1))) unsigned int*)g,
      (__attribute__((address_space(3))) unsigned int*)lds, 16, 0, 0);
}

#define BAR()                                \
  do {                                       \
    asm volatile("" ::: "memory");           \
    __builtin_amdgcn_s_barrier();            \
    asm volatile("" ::: "memory");           \
  } while (0)
#define VMCNT(n) asm volatile("s_waitcnt vmcnt(" #n ")" ::: "memory")

// ---- kernel 1: fused prep (round-14 validated, ~18 us, at BW floor) ----
// blocks [0,1024):    transW — convert+transpose W [K][N] -> Wt [N][K] bf16
// blocks [1024,1536): convX  — 16 rows/block; W[:,0] staged to LDS once per
//   block, then per-row: X fp32->bf16 + fp64 dot vs LDS column -> adj.
__global__ __launch_bounds__(256) void k_prep(const float* __restrict__ W,
    const float* __restrict__ X, const float* __restrict__ b,
    unsigned short* __restrict__ Wt, unsigned short* __restrict__ Xb,
    float* __restrict__ adj) {
  __shared__ float smem[64 * 65];
  const int t = threadIdx.x;
  if (blockIdx.x < 1024) {
    float (*tile)[65] = (float (*)[65])smem;
    const int bx = blockIdx.x & 31;
    const int by = blockIdx.x >> 5;
    const int n0 = bx * 64, k0 = by * 64;
    #pragma unroll
    for (int i = 0; i < 16; ++i) {
      int lin = i * 256 + t;
      int rr = lin >> 6, c = lin & 63;
      tile[rr][c] = W[(size_t)(k0 + rr) * N_DIM + n0 + c];
    }
    __syncthreads();
    #pragma unroll
    for (int i = 0; i < 16; ++i) {
      int lin = i * 256 + t;
      int rr = lin >> 6, c = lin & 63;
      Wt[(size_t)(n0 + rr) * K_DIM + k0 + c] = f2bf(tile[c][rr]);
    }
  } else {
    float* wlds = smem;
    double* red2 = (double*)(smem + 2048);
    const int m0r = (blockIdx.x - 1024) * 16;
    const int w = t >> 6;
    #pragma unroll
    for (int i = 0; i < 8; ++i)
      wlds[t * 8 + i] = W[(size_t)(t * 8 + i) * N_DIM];
    __syncthreads();
    const float4 wv0 = *(const float4*)&wlds[t * 8];
    const float4 wv1 = *(const float4*)&wlds[t * 8 + 4];
    for (int rr = 0; rr < 16; ++rr) {
      const int m = m0r + rr;
      const float4* xr = (const float4*)(X + (size_t)m * K_DIM);
      float4 x0 = xr[2 * t], x1 = xr[2 * t + 1];
      short8 o;
      o[0] = (short)f2bf(x0.x); o[1] = (short)f2bf(x0.y);
      o[2] = (short)f2bf(x0.z); o[3] = (short)f2bf(x0.w);
      o[4] = (short)f2bf(x1.x); o[5] = (short)f2bf(x1.y);
      o[6] = (short)f2bf(x1.z); o[7] = (short)f2bf(x1.w);
      *(short8*)(Xb + (size_t)m * K_DIM + t * 8) = o;
      double s = (double)x0.x * wv0.x + (double)x0.y * wv0.y +
                 (double)x0.z * wv0.z + (double)x0.w * wv0.w +
                 (double)x1.x * wv1.x + (double)x1.y * wv1.y +
                 (double)x1.z * wv1.z + (double)x1.w * wv1.w;
      #pragma unroll
      for (int off = 32; off > 0; off >>= 1) s += __shfl_down(s, off, 64);
      if ((t & 63) == 0) red2[rr * 4 + w] = s;
    }
    __syncthreads();
    if (t < 16) {
      double tot = red2[t * 4] + red2[t * 4 + 1] + red2[t * 4 + 2] +
                   red2[t * 4 + 3] + (double)b[0];
      adj[m0r + t] = (tot > 0.5) ? 1.0f : -1.0f;
    }
  }
}

// ---- kernel 2: 256x256 8-phase GEMM + streamed epilogue ----
// BYTE-IDENTICAL to rounds 13/16 (best measured: GEMM 66.3 us, MfmaUtil
// 41.6-42.5%, 0 bank conflicts; total 88.5 us). Measured optimum across:
// 5 schedule variants (r7-r13), 2 MFMA shapes (r5-r7), 2 occupancy points
// (r15), B-from-L2 (r17 regressed 103us), epilogue streaming (r11, kept),
// prep fusion (r14, kept).
__device__ __forceinline__ void stage_unit(char* ldsc,
    const unsigned short* __restrict__ src, int row0, int kt,
    int isB, int sel, int wid, int l) {
  char* base = ldsc + (size_t)(kt & 1) * 65536 + (size_t)isB * 32768;
  #pragma unroll
  for (int j = 0; j < 2; ++j) {
    int s = wid * 2 + j;               // [0,16) subtile slots of this unit
    int sub_c = s & 1;
    int idx = s >> 1;                  // [0,8)
    int sub_r = isB ? ((idx & 1) + (idx >> 1) * 4 + sel * 2)
                    : ((idx & 3) + ((idx & 4) ? 8 : 0) + sel * 4);
    int grow = row0 + sub_r * 16 + (l >> 2);
    int gcol = kt * 64 + sub_c * 32 + (((l & 3) * 8) ^ ((l & 32) >> 1));
    async16(base + (size_t)(sub_r * 2 + sub_c) * 1024,
            src + (size_t)grow * K_DIM + gcol);
  }
}

__global__ __launch_bounds__(512, 1) void k_gemm8(
    const unsigned short* __restrict__ A,   // Xb [M][K] bf16
    const unsigned short* __restrict__ B,   // Wt [N][K] bf16
    const float* __restrict__ bias,
    const float* __restrict__ adj,
    float* __restrict__ out) {
  __shared__ unsigned short lds[2 * 2 * 256 * 64];   // 128 KB
  char* ldsc = (char*)lds;

  const int t = threadIdx.x;
  const int wid = t >> 6, l = t & 63;
  const int wm = wid >> 2, wn = wid & 3;

  // XCD-bijective swizzle (nwg = 256, 256 % 8 == 0)
  const int bid = blockIdx.x;
  const int swz = (bid & 7) * 32 + (bid >> 3);
  const int bm = swz >> 3, bn = swz & 7;
  const int m0 = bm * 256, n0 = bn * 256;

  const int r = l & 15, q = l >> 4;
  const int rdoff = (r * 64 + q * 16) ^ ((r & 8) << 2);

  const char* ab0 = ldsc;
  const char* bb0 = ldsc + 32768;
  const char* ab1 = ldsc + 65536;
  const char* bb1 = ldsc + 98304;

  f32x4 acc[8][4] = {};
  bf16x8 af0[2][4], af1[2][4], bv0[2][2], bv1[2][2];

#define STG(isB, sel, kt) \
  stage_unit(ldsc, (isB) ? B : A, (isB) ? n0 : m0, kt, isB, sel, wid, l)

#define RD_A(DST, MH, AB)                                                   \
  _Pragma("unroll") for (int mi4 = 0; mi4 < 4; ++mi4) {                     \
    const int sub_r = wm * 8 + (MH) * 4 + mi4;                              \
    _Pragma("unroll") for (int ks = 0; ks < 2; ++ks)                        \
      DST[ks][mi4] =                                                        \
          *(const bf16x8*)((AB) + (size_t)(sub_r * 2 + ks) * 1024 + rdoff); \
  }

#define RD_B(DST, NH, BB)                                                   \
  _Pragma("unroll") for (int ni2 = 0; ni2 < 2; ++ni2) {                     \
    const int sub_r = wn * 4 + (NH) * 2 + ni2;                              \
    _Pragma("unroll") for (int ks = 0; ks < 2; ++ks)                        \
      DST[ks][ni2] =                                                        \
          *(const bf16x8*)((BB) + (size_t)(sub_r * 2 + ks) * 1024 + rdoff); \
  }

#define CL(MH, NH, AF, BV)                                                  \
  __builtin_amdgcn_s_setprio(1);                                            \
  _Pragma("unroll") for (int ks = 0; ks < 2; ++ks)                          \
    _Pragma("unroll") for (int mi4 = 0; mi4 < 4; ++mi4)                     \
      _Pragma("unroll") for (int ni2 = 0; ni2 < 2; ++ni2)                   \
        acc[(MH) * 4 + mi4][(NH) * 2 + ni2] =                               \
            __builtin_amdgcn_mfma_f32_16x16x32_bf16(                        \
                AF[ks][mi4], BV[ks][ni2],                                   \
                acc[(MH) * 4 + mi4][(NH) * 2 + ni2], 0, 0, 0);              \
  __builtin_amdgcn_s_setprio(0);

// streamed quadrant store (16x16 C/D layout, validated rounds 3/4/10)
#define STQ(MH, NH)                                                         \
  _Pragma("unroll") for (int mi4 = 0; mi4 < 4; ++mi4)                       \
    _Pragma("unroll") for (int ni2 = 0; ni2 < 2; ++ni2) {                   \
      const int mi = (MH) * 4 + mi4, ni = (NH) * 2 + ni2;                   \
      const int col = n0 + wn * 64 + ni * 16 + r;                           \
      const int rowb = m0 + wm * 128 + mi * 16 + q * 4;                     \
      _Pragma("unroll") for (int j = 0; j < 4; ++j)                         \
        out[(size_t)(rowb + j) * N_DIM + col] =                             \
            acc[mi][ni][j] + bias_r[ni] + adj_r[mi][j];                     \
    }

#define PH(RD_STMT, STG_STMT, CL_STMT, WAIT_STMT)                           \
  {                                                                         \
    RD_STMT;                                                                \
    STG_STMT;                                                               \
    BAR();                                                                  \
    CL_STMT;                                                                \
    WAIT_STMT;                                                              \
    BAR();                                                                  \
  }

  // ---- prologue: tile 0 (A0,B0,B1,A1) + A0(1),B0(1); retire tile 0 ----
  STG(0, 0, 0); STG(1, 0, 0); STG(1, 1, 0); STG(0, 1, 0);
  STG(0, 0, 1); STG(1, 0, 1);
  VMCNT(4);
  BAR();

  // ---- main loop: 15 iters, 2 K-tiles each ----
  for (int i = 0; i < 15; ++i) {
    const int t1 = 2 * i + 1, t2 = 2 * i + 2, t3 = 2 * i + 3;
    PH(RD_A(af0, 0, ab0); RD_B(bv0, 0, bb0), STG(1, 1, t1),
       CL(0, 0, af0, bv0), );                                   // ph1
    PH(RD_B(bv1, 1, bb0), STG(0, 1, t1), CL(0, 1, af0, bv1), ); // ph2
    PH(RD_A(af1, 1, ab0), STG(0, 0, t2), CL(1, 0, af1, bv0), ); // ph3
    PH(, STG(1, 0, t2), CL(1, 1, af1, bv1), VMCNT(4));          // ph4
    PH(RD_A(af0, 0, ab1); RD_B(bv0, 0, bb1), STG(1, 1, t2),
       CL(0, 0, af0, bv0), );                                   // ph5
    PH(RD_B(bv1, 1, bb1), STG(0, 1, t2), CL(0, 1, af0, bv1), ); // ph6
    PH(RD_A(af1, 1, ab1), STG(0, 0, t3), CL(1, 0, af1, bv0), ); // ph7
    PH(, STG(1, 0, t3), CL(1, 1, af1, bv1), VMCNT(4));          // ph8
  }
  // ---- peeled iter 15 part 1 (tile 30, buf0) ----
  PH(RD_A(af0, 0, ab0); RD_B(bv0, 0, bb0), STG(1, 1, 31),
     CL(0, 0, af0, bv0), );
  PH(RD_B(bv1, 1, bb0), STG(0, 1, 31), CL(0, 1, af0, bv1), );
  PH(RD_A(af1, 1, ab0), , CL(1, 0, af1, bv0), );
  PH(, , CL(1, 1, af1, bv1), VMCNT(0));                         // tile 31 landed

  // ---- prefetch adj/bias for streamed stores (no later vmcnt waits) ----
  float4 adj_r[8];
  float bias_r[4];
  #pragma unroll
  for (int mi = 0; mi < 8; ++mi)
    adj_r[mi] = *(const float4*)&adj[m0 + wm * 128 + mi * 16 + q * 4];
  #pragma unroll
  for (int ni = 0; ni < 4; ++ni)
    bias_r[ni] = bias[n0 + wn * 64 + ni * 16 + r];

  // ---- peeled iter 15 part 2 (tile 31, buf1): streamed epilogue ----
  PH(RD_A(af0, 0, ab1); RD_B(bv0, 0, bb1), , CL(0, 0, af0, bv0); STQ(0, 0), );
  PH(RD_B(bv1, 1, bb1), , CL(0, 1, af0, bv1); STQ(0, 1), );
  PH(RD_A(af1, 1, ab1), , CL(1, 0, af1, bv0); STQ(1, 0), );
  {
    CL(1, 1, af1, bv1);
    STQ(1, 1);
  }

#undef PH
#undef STQ
#undef CL
#undef RD_A
#undef RD_B
#undef STG
}

// ---- fallback path (ws too small): fp32 LDS-tiled GEMM + row adjust ----
__global__ __launch_bounds__(256) void k_gemm_f32(const float* __restrict__ X,
    const float* __restrict__ W, const float* __restrict__ b,
    float* __restrict__ out) {
  __shared__ float As[16][16];
  __shared__ float Bs[16][17];
  const int bn = blockIdx.x & 127, bm = blockIdx.x >> 7;
  const int tx = threadIdx.x & 15, ty = threadIdx.x >> 4;
  const int row = bm * 16 + ty, col = bn * 16 + tx;
  float acc = 0.f;
  for (int k0 = 0; k0 < K_DIM; k0 += 16) {
    As[ty][tx] = X[(size_t)row * K_DIM + k0 + tx];
    Bs[ty][tx] = W[(size_t)(k0 + ty) * N_DIM + col];
    __syncthreads();
    #pragma unroll
    for (int kk = 0; kk < 16; ++kk) acc += As[ty][kk] * Bs[kk][tx];
    __syncthreads();
  }
  out[(size_t)row * N_DIM + col] = acc + b[col];
}

__global__ __launch_bounds__(256) void k_rowadj(float* __restrict__ out) {
  const int m = blockIdx.x;
  const float c0 = out[(size_t)m * N_DIM];
  __syncthreads();
  const float a = (c0 > 0.5f) ? 1.0f : -1.0f;
  for (int n = threadIdx.x; n < N_DIM; n += 256)
    out[(size_t)m * N_DIM + n] += a;
}

extern "C" void kernel_launch(void* const* d_in, const int* in_sizes, int n_in,
                              void* d_out, int out_size, void* d_ws, size_t ws_size,
                              hipStream_t stream) {
  const float* X = (const float*)d_in[0];
  const float* W = (const float*)d_in[1];
  const float* b = (const float*)d_in[2];
  float* out = (float*)d_out;

  const size_t XB_OFF   = 0;
  const size_t WT_OFF   = (size_t)M_DIM * K_DIM * 2;        // 32 MB
  const size_t ADJ_OFF  = WT_OFF + (size_t)N_DIM * K_DIM * 2;
  const size_t NEED     = ADJ_OFF + (size_t)M_DIM * 4;      // ~40 MB

  if (ws_size >= NEED) {
    unsigned short* Xb  = (unsigned short*)((char*)d_ws + XB_OFF);
    unsigned short* Wt  = (unsigned short*)((char*)d_ws + WT_OFF);
    float* adj  = (float*)((char*)d_ws + ADJ_OFF);
    k_prep<<<dim3(1536), dim3(256), 0, stream>>>(W, X, b, Wt, Xb, adj);
    k_gemm8<<<dim3((M_DIM / 256) * (N_DIM / 256)), dim3(512), 0, stream>>>(
        Xb, Wt, b, adj, out);
  } else {
    k_gemm_f32<<<dim3((M_DIM / 16) * (N_DIM / 16)), dim3(256), 0, stream>>>(
        X, W, b, out);
    k_rowadj<<<dim3(M_DIM), dim3(256), 0, stream>>>(out);
  }
}